// Round 10
// baseline (46.604 us; speedup 1.0000x reference)
//
#include <hip/hip_runtime.h>
#include <stdint.h>

typedef __attribute__((ext_vector_type(4))) float  f32x4;
typedef __attribute__((ext_vector_type(8))) __bf16 bf16x8;

#define NB   32
#define CC   512
#define DD   512
#define HW   1024
#define NKS  16      // K-steps of 32

#define WAITL()  asm volatile("s_waitcnt lgkmcnt(0)" ::: "memory")
#define BARR()   do { asm volatile("" ::: "memory"); __builtin_amdgcn_s_barrier(); \
                      asm volatile("" ::: "memory"); } while (0)

// ---------------- pass 1: per-row softmax stats (m, 1/sum) -> ws ------------
// 16 rows/block, 16 lanes/row, coalesced 8 x f32x4 per lane
__global__ __launch_bounds__(256) void stats_kernel(
        const float* __restrict__ atts, float2* __restrict__ stats) {
    const int row = blockIdx.x * 16 + (threadIdx.x >> 4);   // 0..16383
    const int l16 = threadIdx.x & 15;
    const float* a = atts + (size_t)row * DD + l16 * 32;

    f32x4 v[8];
    #pragma unroll
    for (int j = 0; j < 8; ++j) v[j] = *(const f32x4*)(a + j * 4);

    float m = v[0][0];
    #pragma unroll
    for (int j = 0; j < 8; ++j)
        #pragma unroll
        for (int c = 0; c < 4; ++c) m = fmaxf(m, v[j][c]);
    #pragma unroll
    for (int s = 1; s < 16; s <<= 1) m = fmaxf(m, __shfl_xor(m, s, 16));

    float sum = 0.f;
    #pragma unroll
    for (int j = 0; j < 8; ++j)
        #pragma unroll
        for (int c = 0; c < 4; ++c) sum += __expf(v[j][c] - m);
    #pragma unroll
    for (int s = 1; s < 16; s <<= 1) sum += __shfl_xor(sum, s, 16);

    if (l16 == 0) stats[row] = make_float2(m, 1.0f / sum);
}

// ---------------- pass 2: fused regen-GEMM ----------------------------------
// out[n] = softmax(atts[n]) @ images[n]; block = 128 rows x 256 cols, 4 waves
// (exclusive 64-col slices), grid 512 -> 2 independent blocks/CU.
//   lA: 2 x [128][36] bf16 dbuf (pad-36 = conflict-free), coop-staged JIT:
//       atts slice (L2-hot) + precomputed stats -> exp -> bf16. 1-iter prefetch.
//   lB: wave-private [4][64][8] col-XOR plane (R9 mechanics, reg-staged).
//   one 4-wave barrier per K-step; no vmcnt drains (compiler-managed).
__global__ __launch_bounds__(256, 2) void fused_kernel(
        const float* __restrict__ images, const float* __restrict__ atts,
        const float2* __restrict__ stats, float* __restrict__ out) {
    __shared__ unsigned short lA[2][128][36];       // 18 KB
    __shared__ unsigned short lB[4][4][64][8];      // 16 KB

    const int b  = blockIdx.x;       // 0..511
    const int g  = b & 7;            // XCD
    const int q  = b >> 3;           // 0..63
    const int n  = (q >> 4) * 8 + g; // batch; co-resident block pairs share n
    const int rt = (q & 15) >> 2;    // row tile 0..3 (128 rows)
    const int ct = q & 3;            // col tile 0..3 (256 cols)

    const int tid  = threadIdx.x;
    const int lane = tid & 63;
    const int w    = tid >> 6;       // wave 0..3 -> cols ct*256 + w*64
    const int r15  = lane & 15;
    const int kgl  = lane >> 4;

    const float*  gAt = atts + (size_t)n * CC * DD + (size_t)(rt * 128) * DD;
    const float*  gB  = images + (size_t)n * DD * HW + ct * 256 + w * 64;
    float*        gO  = out + (size_t)n * CC * HW + (size_t)(rt * 128) * HW
                            + ct * 256 + w * 64;

    // A staging: thread t covers row t>>1, k-half (t&1)*16 (16 f32 -> 2 bf16x8)
    const int arow  = tid >> 1;
    const int ahalf = tid & 1;
    const float2 st = stats[(size_t)n * CC + rt * 128 + arow];

    f32x4 a4[4];                     // atts prefetch regs (one K-step slice)
    f32x4 breg[8];                   // B prefetch regs
    f32x4 acc[8][4] = {};

    auto loadAt = [&](int kt) {
        const float* p = gAt + (size_t)arow * DD + kt * 32 + ahalf * 16;
        #pragma unroll
        for (int j = 0; j < 4; ++j) a4[j] = *(const f32x4*)(p + j * 4);
    };
    auto stageA = [&](int buf) {
        #pragma unroll
        for (int u = 0; u < 2; ++u) {
            bf16x8 wv;
            #pragma unroll
            for (int e = 0; e < 8; ++e) {
                const float x = a4[u * 2 + (e >> 2)][e & 3];
                wv[e] = (__bf16)(__expf(x - st.x) * st.y);
            }
            *(bf16x8*)&lA[buf][arow][(ahalf * 2 + u) * 8] = wv;
        }
    };
    auto loadB = [&](int kt) {
        const float* p = gB + (size_t)(kt * 32 + kgl * 8) * HW + r15 * 4;
        #pragma unroll
        for (int j = 0; j < 8; ++j)
            breg[j] = *(const f32x4*)(p + (size_t)j * HW);
    };
    auto writeB = [&]() {            // wave-private transpose plane (R9)
        #pragma unroll
        for (int cc = 0; cc < 4; ++cc) {
            bf16x8 wv;
            #pragma unroll
            for (int j = 0; j < 8; ++j) wv[j] = (__bf16)breg[j][cc];
            const int c  = r15 * 4 + cc;
            const int cs = c ^ ((c >> 3) & 3);
            *(bf16x8*)&lB[w][kgl][cs][0] = wv;
        }
    };
    auto compute = [&](int buf) {
        bf16x8 af[8], bv[4];
        #pragma unroll
        for (int m = 0; m < 8; ++m)
            af[m] = *(const bf16x8*)&lA[buf][m * 16 + r15][kgl * 8];
        #pragma unroll
        for (int nf = 0; nf < 4; ++nf) {
            const int c  = nf * 16 + r15;
            const int cs = c ^ ((c >> 3) & 3);
            bv[nf] = *(const bf16x8*)&lB[w][kgl][cs][0];
        }
        #pragma unroll
        for (int m = 0; m < 8; ++m)
            #pragma unroll
            for (int nf = 0; nf < 4; ++nf)
                acc[m][nf] = __builtin_amdgcn_mfma_f32_16x16x32_bf16(
                    af[m], bv[nf], acc[m][nf], 0, 0, 0);
    };

    // ---- prologue: tile 0 staged; atts(1)/B(1) in flight ----
    loadAt(0);
    loadB(0);
    stageA(0);                       // waits a4, ds_write lA[0]
    writeB();                        // waits breg, ds_write lB plane
    loadAt(1);
    loadB(1);
    WAITL();
    BARR();

    // ---- K-loop: one 4-wave barrier per step, no vmcnt drains ----
    #pragma unroll
    for (int kt = 0; kt < NKS; ++kt) {
        const int cur = kt & 1, nxt = cur ^ 1;
        if (kt + 1 < NKS) stageA(nxt);      // consumes a4 = atts(kt+1)
        if (kt + 2 < NKS) loadAt(kt + 2);   // refill a4
        compute(cur);                       // af: lA[cur], bv: lB plane (kt)
        if (kt + 1 < NKS) writeB();         // overwrite plane with B(kt+1)
        if (kt + 2 < NKS) loadB(kt + 2);    // refill breg
        if (kt + 1 < NKS) { WAITL(); BARR(); }
    }

    // ---- epilogue: C/D layout col=lane&15, row=(lane>>4)*4+r ----
    #pragma unroll
    for (int m = 0; m < 8; ++m)
        #pragma unroll
        for (int nf = 0; nf < 4; ++nf)
            #pragma unroll
            for (int r = 0; r < 4; ++r) {
                const int row = m * 16 + kgl * 4 + r;
                const int col = nf * 16 + r15;
                gO[(size_t)row * HW + col] = acc[m][nf][r];
            }
}

extern "C" void kernel_launch(void* const* d_in, const int* in_sizes, int n_in,
                              void* d_out, int out_size, void* d_ws, size_t ws_size,
                              hipStream_t stream) {
    const float* images = (const float*)d_in[0];
    const float* atts   = (const float*)d_in[1];
    float*       out    = (float*)d_out;
    float2*      stats  = (float2*)d_ws;    // 16384 * 8B = 128 KB

    stats_kernel<<<dim3(NB * CC / 16), dim3(256), 0, stream>>>(atts, stats);
    fused_kernel<<<dim3(512), dim3(256), 0, stream>>>(images, atts, stats, out);
}